// Round 8
// baseline (533.055 us; speedup 1.0000x reference)
//
#include <hip/hip_runtime.h>
#include <hip/hip_bf16.h>
#include <math.h>

typedef short bf8v __attribute__((ext_vector_type(8)));   // 8 bf16 (4 VGPRs)
typedef float f32x4 __attribute__((ext_vector_type(4)));
typedef unsigned short u16;
typedef unsigned int u32;

#define DEV __device__ __forceinline__

static constexpr int S_ = 2048;
static constexpr int H_ = 16;
static constexpr int D_ = 64;
static constexpr int DM = 1024;

DEV u16 f2bf(float f) {
  union { float f; u32 u; } v; v.f = f;
  return (u16)((v.u + 0x7fffu + ((v.u >> 16) & 1u)) >> 16);  // RNE
}

DEV u32 pkbf(float a, float b) {  // v_cvt_pk_bf16_f32 via compiler (RNE)
  __hip_bfloat162 h = __float22bfloat162_rn(make_float2(a, b));
  union { __hip_bfloat162 h; u32 u; } v; v.h = h; return v.u;
}

DEV void gld16(u16* lds, const u16* g) {
  __builtin_amdgcn_global_load_lds(
      (const __attribute__((address_space(1))) u32*)g,
      (__attribute__((address_space(3))) u32*)lds, 16, 0, 0);
}

DEV f32x4 MFMA(bf8v a, bf8v b, f32x4 c) {
  return __builtin_amdgcn_mfma_f32_16x16x32_bf16(a, b, c, 0, 0, 0);
}

// ---------------- converts ----------------
__global__ void k_cvt_x(const float* __restrict__ x, u16* __restrict__ xb, int n4) {
  int i = blockIdx.x * blockDim.x + threadIdx.x;
  int stride = gridDim.x * blockDim.x;
  for (; i < n4; i += stride) {
    float4 v = ((const float4*)x)[i];
    ushort4 o;
    o.x = f2bf(v.x); o.y = f2bf(v.y); o.z = f2bf(v.z); o.w = f2bf(v.w);
    ((ushort4*)xb)[i] = o;
  }
}

// W [K][N] f32 -> WT [N][K] bf16, 64x64 LDS tile transpose; z selects matrix
__global__ void k_cvt_wT4(const float* __restrict__ W0, const float* __restrict__ W1,
                          const float* __restrict__ W2, const float* __restrict__ W3,
                          u16* __restrict__ T0, u16* __restrict__ T1,
                          u16* __restrict__ T2, u16* __restrict__ T3) {
  __shared__ float t[64][65];
  const float* W = (blockIdx.z == 0) ? W0 : (blockIdx.z == 1) ? W1 : (blockIdx.z == 2) ? W2 : W3;
  u16* T = (blockIdx.z == 0) ? T0 : (blockIdx.z == 1) ? T1 : (blockIdx.z == 2) ? T2 : T3;
  int n0 = blockIdx.x * 64, k0 = blockIdx.y * 64;
  int x = threadIdx.x, y = threadIdx.y;
#pragma unroll
  for (int i = 0; i < 16; ++i)
    t[y + i * 4][x] = W[(size_t)(k0 + y + i * 4) * DM + n0 + x];
  __syncthreads();
#pragma unroll
  for (int i = 0; i < 16; ++i) {
    int n = y + i * 4;
    T[(size_t)(n0 + n) * DM + k0 + x] = f2bf(t[x][n]);
  }
}

// ---------------- 128x128 GEMM core (A[M][K] bf16, Bt[N][K] bf16, K=1024) ----
DEV void gemm_main(const u16* __restrict__ A, const u16* __restrict__ Bt,
                   int mbase, int nbase, u16* sA, u16* sB, f32x4 (&acc)[4][4]) {
  const int tid = threadIdx.x;
  const int lane = tid & 63, w = tid >> 6;
  const int wm = w >> 1, wn = w & 1;
  const int srow = lane >> 3;                 // 0..7 row within 8-row stage
  const int sslot = (lane & 7) ^ srow;        // pre-swizzled 16B slot
  const int rA = lane & 15, ksl = lane >> 4;

  const u16* Ag = A + (size_t)(mbase + srow) * DM + sslot * 8;
  const u16* Bg = Bt + (size_t)(nbase + srow) * DM + sslot * 8;

  for (int kt = 0; kt < DM; kt += 64) {
    __syncthreads();
#pragma unroll
    for (int i = 0; i < 4; ++i) {
      int rloc = w * 32 + i * 8;              // wave stages rows [w*32, w*32+32)
      gld16(sA + rloc * 64, Ag + (size_t)rloc * DM + kt);
      gld16(sB + rloc * 64, Bg + (size_t)rloc * DM + kt);
    }
    __syncthreads();
    bf8v a[4][2], b[4][2];
#pragma unroll
    for (int mi = 0; mi < 4; ++mi)
#pragma unroll
      for (int kk = 0; kk < 2; ++kk) {
        int r = wm * 64 + mi * 16 + rA;
        a[mi][kk] = *(const bf8v*)(sA + r * 64 + (((kk * 4 + ksl) ^ (lane & 7)) * 8));
      }
#pragma unroll
    for (int nf = 0; nf < 4; ++nf)
#pragma unroll
      for (int kk = 0; kk < 2; ++kk) {
        int r = wn * 64 + nf * 16 + rA;
        b[nf][kk] = *(const bf8v*)(sB + r * 64 + (((kk * 4 + ksl) ^ (lane & 7)) * 8));
      }
#pragma unroll
    for (int kk = 0; kk < 2; ++kk)
#pragma unroll
      for (int mi = 0; mi < 4; ++mi)
#pragma unroll
        for (int nf = 0; nf < 4; ++nf)
          acc[mi][nf] = MFMA(a[mi][kk], b[nf][kk], acc[mi][nf]);
  }
}

// ---------------- QKV projection ----------------
__global__ __launch_bounds__(256, 2) void k_qkv(
    const u16* __restrict__ xb,
    const u16* __restrict__ wqT, const u16* __restrict__ wkT, const u16* __restrict__ wvT,
    const float* __restrict__ bq, const float* __restrict__ bk, const float* __restrict__ bv,
    u16* __restrict__ Q, u16* __restrict__ K, u16* __restrict__ VT) {
  __shared__ u16 sA[128 * 64], sB[128 * 64];
  const int mat = blockIdx.z;
  const u16* Bt = (mat == 0) ? wqT : (mat == 1) ? wkT : wvT;
  const float* bias = (mat == 0) ? bq : (mat == 1) ? bk : bv;
  const int mbase = blockIdx.y * 128, nbase = blockIdx.x * 128;

  f32x4 acc[4][4];
#pragma unroll
  for (int i = 0; i < 4; ++i)
#pragma unroll
    for (int j = 0; j < 4; ++j) acc[i][j] = (f32x4){0.f, 0.f, 0.f, 0.f};

  gemm_main(xb, Bt, mbase, nbase, sA, sB, acc);

  const int lane = threadIdx.x & 63, w = threadIdx.x >> 6;
  const int wm = w >> 1, wn = w & 1;
  const int ksl = lane >> 4, rA = lane & 15;
  const float scale = (mat == 0) ? 0.03125f : 1.0f;  // fold 1/sqrt(1024) into Q
#pragma unroll
  for (int nf = 0; nf < 4; ++nf) {
    const int n = nbase + wn * 64 + nf * 16 + rA;
    const float bb = bias[n];
    const int h = n >> 6, d = n & 63;
#pragma unroll
    for (int mi = 0; mi < 4; ++mi) {
      const int m0 = mbase + wm * 64 + mi * 16 + ksl * 4;
      const int b = m0 >> 11, s = m0 & 2047;
      if (mat == 2) {  // V stored transposed [b][h][d][s]; 4 consecutive s
        ushort4 ov;
        ov.x = f2bf(acc[mi][nf][0] + bb);
        ov.y = f2bf(acc[mi][nf][1] + bb);
        ov.z = f2bf(acc[mi][nf][2] + bb);
        ov.w = f2bf(acc[mi][nf][3] + bb);
        *(ushort4*)&VT[((size_t)(b * H_ + h) * D_ + d) * S_ + s] = ov;
      } else {         // Q/K stored [b][h][s][d]
        u16* dst = (mat == 0) ? Q : K;
#pragma unroll
        for (int reg = 0; reg < 4; ++reg) {
          float vq = (acc[mi][nf][reg] + bb) * scale;
          dst[((size_t)(b * H_ + h) * S_ + (s + reg)) * D_ + d] = f2bf(vq);
        }
      }
    }
  }
}

// ---------------- causal flash attention (barrier-free, swapped QK^T) -------
// One wave = one 16-row q job. S^T = K*Q^T: lane owns q=qmin+col; softmax
// stats lane-local (2 shfl). O^T = V^T*P^T, same lane domain. K/V fragments
// read directly from global (L1/L2-resident). kf for tile t+1 issues right
// after the QK MFMAs consume it. Waves run balanced pairs (p,127-p): 33 tiles.
DEV void attn_job(const u16* __restrict__ Qh, const u16* __restrict__ Kh,
                  const u16* __restrict__ Vh, u16* __restrict__ ctxh,
                  int qmin, u16* pw, int col, int grp) {
  // Q fragments (B-operand of S^T): lane holds Q[q=qmin+col][d=kk*32+grp*8..]
  bf8v qf[2];
#pragma unroll
  for (int kk = 0; kk < 2; ++kk)
    qf[kk] = *(const bf8v*)(Qh + (size_t)(qmin + col) * D_ + kk * 32 + grp * 8);

  f32x4 o[4];
#pragma unroll
  for (int nf = 0; nf < 4; ++nf) o[nf] = (f32x4){0.f, 0.f, 0.f, 0.f};
  float mrow = -INFINITY, lrow = 0.f;

  const int nt = (qmin >> 6) + 1;

  // prologue: K fragments for tile 0
  bf8v kf[4][2];
#pragma unroll
  for (int nf = 0; nf < 4; ++nf)
#pragma unroll
    for (int kk = 0; kk < 2; ++kk)
      kf[nf][kk] = *(const bf8v*)(Kh + (size_t)(nf * 16 + col) * D_ + kk * 32 + grp * 8);

  for (int t = 0; t < nt; ++t) {
    const int kv0 = t * 64;
    // V fragments for tile t (issued before QK; consumed by PV)
    bf8v vf[4][2];
#pragma unroll
    for (int nf = 0; nf < 4; ++nf)
#pragma unroll
      for (int kk = 0; kk < 2; ++kk)
        vf[nf][kk] = *(const bf8v*)(Vh + (size_t)(nf * 16 + col) * S_ + kv0 + kk * 32 + grp * 8);

    f32x4 st[4];
#pragma unroll
    for (int nf = 0; nf < 4; ++nf) st[nf] = (f32x4){0.f, 0.f, 0.f, 0.f};

    __builtin_amdgcn_s_setprio(1);
#pragma unroll
    for (int kk = 0; kk < 2; ++kk)
#pragma unroll
      for (int nf = 0; nf < 4; ++nf)
        st[nf] = MFMA(kf[nf][kk], qf[kk], st[nf]);
    __builtin_amdgcn_s_setprio(0);

    // prefetch K for tile t+1 (WAR on issued MFMAs; hides under softmax+PV)
    if (t + 1 < nt) {
      const int kvn = kv0 + 64;
#pragma unroll
      for (int nf = 0; nf < 4; ++nf)
#pragma unroll
        for (int kk = 0; kk < 2; ++kk)
          kf[nf][kk] = *(const bf8v*)(Kh + (size_t)(kvn + nf * 16 + col) * D_ + kk * 32 + grp * 8);
    }

    if (t == nt - 1) {  // causal mask: only the last tile straddles
      const int q = qmin + col;
#pragma unroll
      for (int nf = 0; nf < 4; ++nf)
#pragma unroll
        for (int reg = 0; reg < 4; ++reg) {
          int kv = kv0 + nf * 16 + grp * 4 + reg;
          if (kv > q) st[nf][reg] = -INFINITY;
        }
    }

    // online softmax: lane owns q=qmin+col; 16 in-lane values + 2 shfl
    {
      float tm = st[0][0];
#pragma unroll
      for (int nf = 0; nf < 4; ++nf)
        tm = fmaxf(tm, fmaxf(fmaxf(st[nf][0], st[nf][1]),
                             fmaxf(st[nf][2], st[nf][3])));
      tm = fmaxf(tm, __shfl_xor(tm, 16));
      tm = fmaxf(tm, __shfl_xor(tm, 32));
      float mnew = fmaxf(mrow, tm);
      float corr = __expf(mrow - mnew);
      float ps = 0.f;
#pragma unroll
      for (int nf = 0; nf < 4; ++nf)
#pragma unroll
        for (int reg = 0; reg < 4; ++reg) {
          float p = __expf(st[nf][reg] - mnew);
          st[nf][reg] = p;
          ps += p;
        }
      ps += __shfl_xor(ps, 16);
      ps += __shfl_xor(ps, 32);
      lrow = lrow * corr + ps;
      mrow = mnew;
#pragma unroll
      for (int nf = 0; nf < 4; ++nf) o[nf] *= corr;

      // P write: lane holds P[q][kv=nf*16+grp*4+reg] -> 4 consecutive kv
#pragma unroll
      for (int nf = 0; nf < 4; ++nf) {
        const int slot = (nf * 2 + (grp >> 1)) ^ (col & 7);
        *(uint2*)(pw + col * 64 + slot * 8 + (grp & 1) * 4) =
            make_uint2(pkbf(st[nf][0], st[nf][1]), pkbf(st[nf][2], st[nf][3]));
      }
    }

    // P read (B-operand): lane needs P[q=col][kv=kk*32+grp*8..] (b128)
    bf8v pf[2];
#pragma unroll
    for (int kk = 0; kk < 2; ++kk) {
      const int slot = (kk * 4 + grp) ^ (col & 7);
      pf[kk] = *(const bf8v*)(pw + col * 64 + slot * 8);
    }

    __builtin_amdgcn_s_setprio(1);
#pragma unroll
    for (int kk = 0; kk < 2; ++kk)
#pragma unroll
      for (int nf = 0; nf < 4; ++nf)
        o[nf] = MFMA(vf[nf][kk], pf[kk], o[nf]);
    __builtin_amdgcn_s_setprio(0);
  }

  // epilogue: O^T layout col q = col, row d = nf*16+grp*4+reg
  {
    const float inv = 1.f / lrow;
    const int q = qmin + col;
#pragma unroll
    for (int nf = 0; nf < 4; ++nf) {
      *(uint2*)&ctxh[(size_t)q * DM + nf * 16 + grp * 4] =
          make_uint2(pkbf(o[nf][0] * inv, o[nf][1] * inv),
                     pkbf(o[nf][2] * inv, o[nf][3] * inv));
    }
  }
}

__global__ __launch_bounds__(256, 4) void k_attn(
    const u16* __restrict__ Q, const u16* __restrict__ K, const u16* __restrict__ VT,
    u16* __restrict__ ctx) {
  __shared__ u16 sP[4][16 * 64];  // per-wave P buffer, XOR-swizzled 16B slots
  const int g = blockIdx.x;                  // 1024 blocks
  const int xcd = g & 7, idx = g >> 3;       // idx 0..127
  const int bh = xcd * 8 + (idx >> 4);       // 8 consecutive bh per XCD
  const int tid = threadIdx.x, lane = tid & 63, w = tid >> 6;
  const int p = (idx & 15) * 4 + w;          // pair index 0..63
  const int col = lane & 15, grp = lane >> 4;

  const u16* Qh = Q + (size_t)bh * S_ * D_;
  const u16* Kh = K + (size_t)bh * S_ * D_;
  const u16* Vh = VT + (size_t)bh * D_ * S_;
  u16* ctxh = ctx + ((size_t)(bh >> 4) * S_) * DM + (bh & 15) * 64;
  u16* pw = sP[w];

  // balanced pair: cost (p/4+1) + ((127-p)/4+1) = 33 tiles for every wave
  attn_job(Qh, Kh, Vh, ctxh, 16 * p, pw, col, grp);
  attn_job(Qh, Kh, Vh, ctxh, 16 * (127 - p), pw, col, grp);
}

// ---------------- output projection (fp32 out) ----------------
__global__ __launch_bounds__(256, 2) void k_oproj(
    const u16* __restrict__ ctx, const u16* __restrict__ woT,
    const float* __restrict__ bo, float* __restrict__ out) {
  __shared__ u16 sA[128 * 64], sB[128 * 64];
  const int mbase = blockIdx.y * 128, nbase = blockIdx.x * 128;
  f32x4 acc[4][4];
#pragma unroll
  for (int i = 0; i < 4; ++i)
#pragma unroll
    for (int j = 0; j < 4; ++j) acc[i][j] = (f32x4){0.f, 0.f, 0.f, 0.f};

  gemm_main(ctx, woT, mbase, nbase, sA, sB, acc);

  const int lane = threadIdx.x & 63, w = threadIdx.x >> 6;
  const int wm = w >> 1, wn = w & 1;
  const int ksl = lane >> 4, rA = lane & 15;
#pragma unroll
  for (int nf = 0; nf < 4; ++nf) {
    const int n = nbase + wn * 64 + nf * 16 + rA;
    const float bb = bo[n];
#pragma unroll
    for (int mi = 0; mi < 4; ++mi) {
      const int m0 = mbase + wm * 64 + mi * 16 + ksl * 4;
#pragma unroll
      for (int reg = 0; reg < 4; ++reg)
        out[(size_t)(m0 + reg) * DM + n] = acc[mi][nf][reg] + bb;
    }
  }
}

extern "C" void kernel_launch(void* const* d_in, const int* in_sizes, int n_in,
                              void* d_out, int out_size, void* d_ws, size_t ws_size,
                              hipStream_t stream) {
  const float* x  = (const float*)d_in[0];
  const float* Wq = (const float*)d_in[1];
  const float* bq = (const float*)d_in[2];
  const float* Wk = (const float*)d_in[3];
  const float* bk = (const float*)d_in[4];
  const float* Wv = (const float*)d_in[5];
  const float* bv = (const float*)d_in[6];
  const float* Wo = (const float*)d_in[7];
  const float* bo = (const float*)d_in[8];
  float* out = (float*)d_out;

  char* ws = (char*)d_ws;
  u16* xb  = (u16*)(ws);
  u16* wqT = (u16*)(ws + (size_t)(16u << 20));
  u16* wkT = (u16*)(ws + (size_t)(18u << 20));
  u16* wvT = (u16*)(ws + (size_t)(20u << 20));
  u16* woT = (u16*)(ws + (size_t)(22u << 20));
  u16* Qd  = (u16*)(ws + (size_t)(24u << 20));
  u16* Kd  = (u16*)(ws + (size_t)(40u << 20));
  u16* VTd = (u16*)(ws + (size_t)(56u << 20));
  u16* ctx = xb;  // xb dead after k_qkv; stream-ordered reuse

  k_cvt_x<<<2048, 256, 0, stream>>>(x, xb, (8192 * 1024) / 4);
  k_cvt_wT4<<<dim3(16, 16, 4), dim3(64, 4), 0, stream>>>(Wq, Wk, Wv, Wo, wqT, wkT, wvT, woT);
  k_qkv<<<dim3(8, 64, 3), 256, 0, stream>>>(xb, wqT, wkT, wvT, bq, bk, bv, Qd, Kd, VTd);
  k_attn<<<1024, 256, 0, stream>>>(Qd, Kd, VTd, ctx);
  k_oproj<<<dim3(8, 64), 256, 0, stream>>>(ctx, woT, bo, out);
}

// Round 10
// 451.352 us; speedup vs baseline: 1.1810x; 1.1810x over previous
//
#include <hip/hip_runtime.h>
#include <hip/hip_bf16.h>
#include <math.h>

typedef short bf8v __attribute__((ext_vector_type(8)));   // 8 bf16 (4 VGPRs)
typedef float f32x4 __attribute__((ext_vector_type(4)));
typedef unsigned short u16;
typedef unsigned int u32;

#define DEV __device__ __forceinline__

static constexpr int S_ = 2048;
static constexpr int H_ = 16;
static constexpr int D_ = 64;
static constexpr int DM = 1024;

DEV u16 f2bf(float f) {
  union { float f; u32 u; } v; v.f = f;
  return (u16)((v.u + 0x7fffu + ((v.u >> 16) & 1u)) >> 16);  // RNE
}

DEV u32 pkbf(float a, float b) {  // v_cvt_pk_bf16_f32 via compiler (RNE)
  __hip_bfloat162 h = __float22bfloat162_rn(make_float2(a, b));
  union { __hip_bfloat162 h; u32 u; } v; v.h = h; return v.u;
}

DEV void gld16(u16* lds, const u16* g) {
  __builtin_amdgcn_global_load_lds(
      (const __attribute__((address_space(1))) u32*)g,
      (__attribute__((address_space(3))) u32*)lds, 16, 0, 0);
}

DEV f32x4 MFMA(bf8v a, bf8v b, f32x4 c) {
  return __builtin_amdgcn_mfma_f32_16x16x32_bf16(a, b, c, 0, 0, 0);
}

// ---------------- converts ----------------
__global__ void k_cvt_x(const float* __restrict__ x, u16* __restrict__ xb, int n4) {
  int i = blockIdx.x * blockDim.x + threadIdx.x;
  int stride = gridDim.x * blockDim.x;
  for (; i < n4; i += stride) {
    float4 v = ((const float4*)x)[i];
    ushort4 o;
    o.x = f2bf(v.x); o.y = f2bf(v.y); o.z = f2bf(v.z); o.w = f2bf(v.w);
    ((ushort4*)xb)[i] = o;
  }
}

// W [K][N] f32 -> WT [N][K] bf16, 64x64 LDS tile transpose; z selects matrix
__global__ void k_cvt_wT4(const float* __restrict__ W0, const float* __restrict__ W1,
                          const float* __restrict__ W2, const float* __restrict__ W3,
                          u16* __restrict__ T0, u16* __restrict__ T1,
                          u16* __restrict__ T2, u16* __restrict__ T3) {
  __shared__ float t[64][65];
  const float* W = (blockIdx.z == 0) ? W0 : (blockIdx.z == 1) ? W1 : (blockIdx.z == 2) ? W2 : W3;
  u16* T = (blockIdx.z == 0) ? T0 : (blockIdx.z == 1) ? T1 : (blockIdx.z == 2) ? T2 : T3;
  int n0 = blockIdx.x * 64, k0 = blockIdx.y * 64;
  int x = threadIdx.x, y = threadIdx.y;
#pragma unroll
  for (int i = 0; i < 16; ++i)
    t[y + i * 4][x] = W[(size_t)(k0 + y + i * 4) * DM + n0 + x];
  __syncthreads();
#pragma unroll
  for (int i = 0; i < 16; ++i) {
    int n = y + i * 4;
    T[(size_t)(n0 + n) * DM + k0 + x] = f2bf(t[x][n]);
  }
}

// ---------------- 128x128 GEMM core (A[M][K] bf16, Bt[N][K] bf16, K=1024) ----
DEV void gemm_main(const u16* __restrict__ A, const u16* __restrict__ Bt,
                   int mbase, int nbase, u16* sA, u16* sB, f32x4 (&acc)[4][4]) {
  const int tid = threadIdx.x;
  const int lane = tid & 63, w = tid >> 6;
  const int wm = w >> 1, wn = w & 1;
  const int srow = lane >> 3;                 // 0..7 row within 8-row stage
  const int sslot = (lane & 7) ^ srow;        // pre-swizzled 16B slot
  const int rA = lane & 15, ksl = lane >> 4;

  const u16* Ag = A + (size_t)(mbase + srow) * DM + sslot * 8;
  const u16* Bg = Bt + (size_t)(nbase + srow) * DM + sslot * 8;

  for (int kt = 0; kt < DM; kt += 64) {
    __syncthreads();
#pragma unroll
    for (int i = 0; i < 4; ++i) {
      int rloc = w * 32 + i * 8;              // wave stages rows [w*32, w*32+32)
      gld16(sA + rloc * 64, Ag + (size_t)rloc * DM + kt);
      gld16(sB + rloc * 64, Bg + (size_t)rloc * DM + kt);
    }
    __syncthreads();
    bf8v a[4][2], b[4][2];
#pragma unroll
    for (int mi = 0; mi < 4; ++mi)
#pragma unroll
      for (int kk = 0; kk < 2; ++kk) {
        int r = wm * 64 + mi * 16 + rA;
        a[mi][kk] = *(const bf8v*)(sA + r * 64 + (((kk * 4 + ksl) ^ (lane & 7)) * 8));
      }
#pragma unroll
    for (int nf = 0; nf < 4; ++nf)
#pragma unroll
      for (int kk = 0; kk < 2; ++kk) {
        int r = wn * 64 + nf * 16 + rA;
        b[nf][kk] = *(const bf8v*)(sB + r * 64 + (((kk * 4 + ksl) ^ (lane & 7)) * 8));
      }
#pragma unroll
    for (int kk = 0; kk < 2; ++kk)
#pragma unroll
      for (int mi = 0; mi < 4; ++mi)
#pragma unroll
        for (int nf = 0; nf < 4; ++nf)
          acc[mi][nf] = MFMA(a[mi][kk], b[nf][kk], acc[mi][nf]);
  }
}

// ---------------- QKV projection ----------------
__global__ __launch_bounds__(256, 2) void k_qkv(
    const u16* __restrict__ xb,
    const u16* __restrict__ wqT, const u16* __restrict__ wkT, const u16* __restrict__ wvT,
    const float* __restrict__ bq, const float* __restrict__ bk, const float* __restrict__ bv,
    u16* __restrict__ Q, u16* __restrict__ K, u16* __restrict__ VT) {
  __shared__ u16 sA[128 * 64], sB[128 * 64];
  const int mat = blockIdx.z;
  const u16* Bt = (mat == 0) ? wqT : (mat == 1) ? wkT : wvT;
  const float* bias = (mat == 0) ? bq : (mat == 1) ? bk : bv;
  const int mbase = blockIdx.y * 128, nbase = blockIdx.x * 128;

  f32x4 acc[4][4];
#pragma unroll
  for (int i = 0; i < 4; ++i)
#pragma unroll
    for (int j = 0; j < 4; ++j) acc[i][j] = (f32x4){0.f, 0.f, 0.f, 0.f};

  gemm_main(xb, Bt, mbase, nbase, sA, sB, acc);

  const int lane = threadIdx.x & 63, w = threadIdx.x >> 6;
  const int wm = w >> 1, wn = w & 1;
  const int ksl = lane >> 4, rA = lane & 15;
  const float scale = (mat == 0) ? 0.03125f : 1.0f;  // fold 1/sqrt(1024) into Q
#pragma unroll
  for (int nf = 0; nf < 4; ++nf) {
    const int n = nbase + wn * 64 + nf * 16 + rA;
    const float bb = bias[n];
    const int h = n >> 6, d = n & 63;
#pragma unroll
    for (int mi = 0; mi < 4; ++mi) {
      const int m0 = mbase + wm * 64 + mi * 16 + ksl * 4;
      const int b = m0 >> 11, s = m0 & 2047;
      if (mat == 2) {  // V stored transposed [b][h][d][s]; 4 consecutive s
        ushort4 ov;
        ov.x = f2bf(acc[mi][nf][0] + bb);
        ov.y = f2bf(acc[mi][nf][1] + bb);
        ov.z = f2bf(acc[mi][nf][2] + bb);
        ov.w = f2bf(acc[mi][nf][3] + bb);
        *(ushort4*)&VT[((size_t)(b * H_ + h) * D_ + d) * S_ + s] = ov;
      } else {         // Q/K stored [b][h][s][d]
        u16* dst = (mat == 0) ? Q : K;
#pragma unroll
        for (int reg = 0; reg < 4; ++reg) {
          float vq = (acc[mi][nf][reg] + bb) * scale;
          dst[((size_t)(b * H_ + h) * S_ + (s + reg)) * D_ + d] = f2bf(vq);
        }
      }
    }
  }
}

// ---------------- causal flash attention (barrier-free, swapped QK^T) -------
// One wave = one 16-row q job. S^T = K*Q^T: lane owns q=qmin+col; softmax
// stats lane-local (2 shfl). O^T = V^T*P^T, same lane domain. K/V fragments
// read directly from global (L1/L2-resident). kf for tile t+1 issues right
// after the QK MFMAs consume it. Waves run balanced pairs (p,127-p): 33 tiles.
// NOTE: launch_bounds min-waves stays at 2 — (256,4) clamped VGPRs to 64 and
// spilled the kf/vf MFMA operands to scratch (R8: WRITE_SIZE 16->363 MB).
DEV void attn_job(const u16* __restrict__ Qh, const u16* __restrict__ Kh,
                  const u16* __restrict__ Vh, u16* __restrict__ ctxh,
                  int qmin, u16* pw, int col, int grp) {
  // Q fragments (B-operand of S^T): lane holds Q[q=qmin+col][d=kk*32+grp*8..]
  bf8v qf[2];
#pragma unroll
  for (int kk = 0; kk < 2; ++kk)
    qf[kk] = *(const bf8v*)(Qh + (size_t)(qmin + col) * D_ + kk * 32 + grp * 8);

  f32x4 o[4];
#pragma unroll
  for (int nf = 0; nf < 4; ++nf) o[nf] = (f32x4){0.f, 0.f, 0.f, 0.f};
  float mrow = -INFINITY, lrow = 0.f;

  const int nt = (qmin >> 6) + 1;

  // prologue: K fragments for tile 0
  bf8v kf[4][2];
#pragma unroll
  for (int nf = 0; nf < 4; ++nf)
#pragma unroll
    for (int kk = 0; kk < 2; ++kk)
      kf[nf][kk] = *(const bf8v*)(Kh + (size_t)(nf * 16 + col) * D_ + kk * 32 + grp * 8);

  for (int t = 0; t < nt; ++t) {
    const int kv0 = t * 64;
    // V fragments for tile t (issued before QK; consumed by PV)
    bf8v vf[4][2];
#pragma unroll
    for (int nf = 0; nf < 4; ++nf)
#pragma unroll
      for (int kk = 0; kk < 2; ++kk)
        vf[nf][kk] = *(const bf8v*)(Vh + (size_t)(nf * 16 + col) * S_ + kv0 + kk * 32 + grp * 8);

    f32x4 st[4];
#pragma unroll
    for (int nf = 0; nf < 4; ++nf) st[nf] = (f32x4){0.f, 0.f, 0.f, 0.f};

    __builtin_amdgcn_s_setprio(1);
#pragma unroll
    for (int kk = 0; kk < 2; ++kk)
#pragma unroll
      for (int nf = 0; nf < 4; ++nf)
        st[nf] = MFMA(kf[nf][kk], qf[kk], st[nf]);
    __builtin_amdgcn_s_setprio(0);

    // prefetch K for tile t+1 (WAR on issued MFMAs; hides under softmax+PV)
    if (t + 1 < nt) {
      const int kvn = kv0 + 64;
#pragma unroll
      for (int nf = 0; nf < 4; ++nf)
#pragma unroll
        for (int kk = 0; kk < 2; ++kk)
          kf[nf][kk] = *(const bf8v*)(Kh + (size_t)(kvn + nf * 16 + col) * D_ + kk * 32 + grp * 8);
    }

    if (t == nt - 1) {  // causal mask: only the last tile straddles
      const int q = qmin + col;
#pragma unroll
      for (int nf = 0; nf < 4; ++nf)
#pragma unroll
        for (int reg = 0; reg < 4; ++reg) {
          int kv = kv0 + nf * 16 + grp * 4 + reg;
          if (kv > q) st[nf][reg] = -INFINITY;
        }
    }

    // online softmax: lane owns q=qmin+col; 16 in-lane values + 2 shfl
    {
      float tm = st[0][0];
#pragma unroll
      for (int nf = 0; nf < 4; ++nf)
        tm = fmaxf(tm, fmaxf(fmaxf(st[nf][0], st[nf][1]),
                             fmaxf(st[nf][2], st[nf][3])));
      tm = fmaxf(tm, __shfl_xor(tm, 16));
      tm = fmaxf(tm, __shfl_xor(tm, 32));
      float mnew = fmaxf(mrow, tm);
      float corr = __expf(mrow - mnew);
      float ps = 0.f;
#pragma unroll
      for (int nf = 0; nf < 4; ++nf)
#pragma unroll
        for (int reg = 0; reg < 4; ++reg) {
          float p = __expf(st[nf][reg] - mnew);
          st[nf][reg] = p;
          ps += p;
        }
      ps += __shfl_xor(ps, 16);
      ps += __shfl_xor(ps, 32);
      lrow = lrow * corr + ps;
      mrow = mnew;
#pragma unroll
      for (int nf = 0; nf < 4; ++nf) o[nf] *= corr;

      // P write: lane holds P[q][kv=nf*16+grp*4+reg] -> 4 consecutive kv
#pragma unroll
      for (int nf = 0; nf < 4; ++nf) {
        const int slot = (nf * 2 + (grp >> 1)) ^ (col & 7);
        *(uint2*)(pw + col * 64 + slot * 8 + (grp & 1) * 4) =
            make_uint2(pkbf(st[nf][0], st[nf][1]), pkbf(st[nf][2], st[nf][3]));
      }
    }

    // P read (B-operand): lane needs P[q=col][kv=kk*32+grp*8..] (b128)
    bf8v pf[2];
#pragma unroll
    for (int kk = 0; kk < 2; ++kk) {
      const int slot = (kk * 4 + grp) ^ (col & 7);
      pf[kk] = *(const bf8v*)(pw + col * 64 + slot * 8);
    }

    __builtin_amdgcn_s_setprio(1);
#pragma unroll
    for (int kk = 0; kk < 2; ++kk)
#pragma unroll
      for (int nf = 0; nf < 4; ++nf)
        o[nf] = MFMA(vf[nf][kk], pf[kk], o[nf]);
    __builtin_amdgcn_s_setprio(0);
  }

  // epilogue: O^T layout col q = col, row d = nf*16+grp*4+reg
  {
    const float inv = 1.f / lrow;
    const int q = qmin + col;
#pragma unroll
    for (int nf = 0; nf < 4; ++nf) {
      *(uint2*)&ctxh[(size_t)q * DM + nf * 16 + grp * 4] =
          make_uint2(pkbf(o[nf][0] * inv, o[nf][1] * inv),
                     pkbf(o[nf][2] * inv, o[nf][3] * inv));
    }
  }
}

__global__ __launch_bounds__(256, 2) void k_attn(
    const u16* __restrict__ Q, const u16* __restrict__ K, const u16* __restrict__ VT,
    u16* __restrict__ ctx) {
  __shared__ u16 sP[4][16 * 64];  // per-wave P buffer, XOR-swizzled 16B slots
  const int g = blockIdx.x;                  // 1024 blocks
  const int xcd = g & 7, idx = g >> 3;       // idx 0..127
  const int bh = xcd * 8 + (idx >> 4);       // 8 consecutive bh per XCD
  const int tid = threadIdx.x, lane = tid & 63, w = tid >> 6;
  const int p = (idx & 15) * 4 + w;          // pair index 0..63
  const int col = lane & 15, grp = lane >> 4;

  const u16* Qh = Q + (size_t)bh * S_ * D_;
  const u16* Kh = K + (size_t)bh * S_ * D_;
  const u16* Vh = VT + (size_t)bh * D_ * S_;
  u16* ctxh = ctx + ((size_t)(bh >> 4) * S_) * DM + (bh & 15) * 64;
  u16* pw = sP[w];

  // balanced pair: cost (p/4+1) + ((127-p)/4+1) = 33 tiles for every wave
  attn_job(Qh, Kh, Vh, ctxh, 16 * p, pw, col, grp);
  attn_job(Qh, Kh, Vh, ctxh, 16 * (127 - p), pw, col, grp);
}

// ---------------- output projection (fp32 out) ----------------
__global__ __launch_bounds__(256, 2) void k_oproj(
    const u16* __restrict__ ctx, const u16* __restrict__ woT,
    const float* __restrict__ bo, float* __restrict__ out) {
  __shared__ u16 sA[128 * 64], sB[128 * 64];
  const int mbase = blockIdx.y * 128, nbase = blockIdx.x * 128;
  f32x4 acc[4][4];
#pragma unroll
  for (int i = 0; i < 4; ++i)
#pragma unroll
    for (int j = 0; j < 4; ++j) acc[i][j] = (f32x4){0.f, 0.f, 0.f, 0.f};

  gemm_main(ctx, woT, mbase, nbase, sA, sB, acc);

  const int lane = threadIdx.x & 63, w = threadIdx.x >> 6;
  const int wm = w >> 1, wn = w & 1;
  const int ksl = lane >> 4, rA = lane & 15;
#pragma unroll
  for (int nf = 0; nf < 4; ++nf) {
    const int n = nbase + wn * 64 + nf * 16 + rA;
    const float bb = bo[n];
#pragma unroll
    for (int mi = 0; mi < 4; ++mi) {
      const int m0 = mbase + wm * 64 + mi * 16 + ksl * 4;
#pragma unroll
      for (int reg = 0; reg < 4; ++reg)
        out[(size_t)(m0 + reg) * DM + n] = acc[mi][nf][reg] + bb;
    }
  }
}

extern "C" void kernel_launch(void* const* d_in, const int* in_sizes, int n_in,
                              void* d_out, int out_size, void* d_ws, size_t ws_size,
                              hipStream_t stream) {
  const float* x  = (const float*)d_in[0];
  const float* Wq = (const float*)d_in[1];
  const float* bq = (const float*)d_in[2];
  const float* Wk = (const float*)d_in[3];
  const float* bk = (const float*)d_in[4];
  const float* Wv = (const float*)d_in[5];
  const float* bv = (const float*)d_in[6];
  const float* Wo = (const float*)d_in[7];
  const float* bo = (const float*)d_in[8];
  float* out = (float*)d_out;

  char* ws = (char*)d_ws;
  u16* xb  = (u16*)(ws);
  u16* wqT = (u16*)(ws + (size_t)(16u << 20));
  u16* wkT = (u16*)(ws + (size_t)(18u << 20));
  u16* wvT = (u16*)(ws + (size_t)(20u << 20));
  u16* woT = (u16*)(ws + (size_t)(22u << 20));
  u16* Qd  = (u16*)(ws + (size_t)(24u << 20));
  u16* Kd  = (u16*)(ws + (size_t)(40u << 20));
  u16* VTd = (u16*)(ws + (size_t)(56u << 20));
  u16* ctx = xb;  // xb dead after k_qkv; stream-ordered reuse

  k_cvt_x<<<2048, 256, 0, stream>>>(x, xb, (8192 * 1024) / 4);
  k_cvt_wT4<<<dim3(16, 16, 4), dim3(64, 4), 0, stream>>>(Wq, Wk, Wv, Wo, wqT, wkT, wvT, woT);
  k_qkv<<<dim3(8, 64, 3), 256, 0, stream>>>(xb, wqT, wkT, wvT, bq, bk, bv, Qd, Kd, VTd);
  k_attn<<<1024, 256, 0, stream>>>(Qd, Kd, VTd, ctx);
  k_oproj<<<dim3(8, 64), 256, 0, stream>>>(ctx, woT, bo, out);
}